// Round 3
// baseline (214.248 us; speedup 1.0000x reference)
//
#include <hip/hip_runtime.h>
#include <stdint.h>

// ---------------- problem constants ----------------
#define BHN 16          // b*h flat batch
#define TLEN 4096
#define EDIM 64
#define NHASH 8
#define NBUCK 64
#define GBUCK 512
#define NCHUNK 512
#define NITEMS 32768

// ---------------- workspace layout (bytes) ----------------
#define WS_BUCKETS 0u                 // 16*8*4096 u8          = 524288
#define WS_STARTS  524288u            // 16*512 int            = 32768
#define WS_SORTED  557056u            // 16*32768 int          = 2097152
#define WS_LSE     2654208u           // 16*8*4096 f32         = 2097152
#define WS_O       4751360u           // 16*8*4096*64 fp16     = 67108864

typedef __attribute__((ext_vector_type(4))) float f32x4;
typedef __attribute__((ext_vector_type(8))) _Float16 f16x8;     // MFMA A/B frag
typedef __attribute__((ext_vector_type(4))) _Float16 f16x4;
typedef __attribute__((ext_vector_type(4))) unsigned short u16x4;

#define LOG2E 1.44269504088896f
#define LN2   0.69314718055995f

static __device__ __forceinline__ unsigned short f2h_bits(float x) {
  _Float16 h = (_Float16)x;
  return *(unsigned short*)&h;
}

// ============================================================
// K1: LSH hash. Split over 4x blocks: each thread does hashes
// {2*hp, 2*hp+1} for one (bh,t). Arithmetic chain identical to
// the round-1 kernel (argmax ties must not move).
// ============================================================
__global__ __launch_bounds__(256) void k_hash(const float* __restrict__ qk,
                                              const float* __restrict__ rot,
                                              uint8_t* __restrict__ buckets,
                                              int* __restrict__ counts) {
  __shared__ __attribute__((aligned(16))) float rot_s[64 * 64]; // [f][hh*32+i]
  int tid = threadIdx.x;
  int gid = blockIdx.x * 256 + tid;          // < 262144
  int bh = gid >> 14;
  int hp = (gid >> 12) & 3;
  int t  = gid & 4095;
  int b = bh >> 3, head = bh & 7;

  // stage rotations for this hash pair: global row stride 64 float4s
  for (int k = tid; k < 1024; k += 256) {
    int f = k >> 4, c4 = k & 15;
    ((float4*)rot_s)[k] = ((const float4*)rot)[f * 64 + hp * 16 + c4];
  }
  __syncthreads();

  const float4* row4 = (const float4*)(qk + ((size_t)((b * 4096 + t) * 8 + head)) * 64);
  float q[64];
#pragma unroll
  for (int f4 = 0; f4 < 16; ++f4) {
    float4 vv = row4[f4];
    q[4 * f4 + 0] = vv.x; q[4 * f4 + 1] = vv.y;
    q[4 * f4 + 2] = vv.z; q[4 * f4 + 3] = vv.w;
  }

  for (int hh = 0; hh < 2; ++hh) {
    int h = hp * 2 + hh;
    float acc[32];
#pragma unroll
    for (int i = 0; i < 32; ++i) acc[i] = 0.f;
    const float* rb = rot_s + hh * 32;
#pragma unroll
    for (int f = 0; f < 64; ++f) {
      float qf = q[f];
      const float4* rp = (const float4*)(rb + f * 64);
#pragma unroll
      for (int i4 = 0; i4 < 8; ++i4) {
        float4 rv = rp[i4];
        acc[4 * i4 + 0] = fmaf(qf, rv.x, acc[4 * i4 + 0]);
        acc[4 * i4 + 1] = fmaf(qf, rv.y, acc[4 * i4 + 1]);
        acc[4 * i4 + 2] = fmaf(qf, rv.z, acc[4 * i4 + 2]);
        acc[4 * i4 + 3] = fmaf(qf, rv.w, acc[4 * i4 + 3]);
      }
    }
    float bv = acc[0]; int bi = 0;
#pragma unroll
    for (int i = 1; i < 32; ++i) { if (acc[i] > bv) { bv = acc[i]; bi = i; } }
#pragma unroll
    for (int i = 0; i < 32; ++i) { float nv = -acc[i]; if (nv > bv) { bv = nv; bi = i + 32; } }

    buckets[(bh * 8 + h) * 4096 + t] = (uint8_t)bi;
    atomicAdd(&counts[bh * 512 + h * 64 + bi], 1);
  }
}

// ============================================================
// K2a: exclusive scan (unchanged)
// ============================================================
__global__ __launch_bounds__(512) void k_scan(int* __restrict__ counts) {
  __shared__ int s[512];
  int tid = threadIdx.x;
  int bh = blockIdx.x;
  s[tid] = counts[bh * 512 + tid];
  __syncthreads();
#pragma unroll
  for (int off = 1; off < 512; off <<= 1) {
    int v = (tid >= off) ? s[tid - off] : 0;
    __syncthreads();
    s[tid] += v;
    __syncthreads();
  }
  counts[bh * 512 + tid] = (tid == 0) ? 0 : s[tid - 1];
}

// ============================================================
// K2b: stable rank + scatter (unchanged)
// ============================================================
__global__ __launch_bounds__(64) void k_rank(const uint8_t* __restrict__ buckets,
                                             const int* __restrict__ starts,
                                             int* __restrict__ sorted) {
  __shared__ uint8_t bkt[4096];
  __shared__ uint8_t lrk[4096];
  __shared__ int hist[64 * 65];
  __shared__ int sbase[64];
  int tid = threadIdx.x;
  int bh = blockIdx.x >> 3, h = blockIdx.x & 7;

  const int* src = (const int*)(buckets + (size_t)(bh * 8 + h) * 4096);
  for (int k = tid; k < 1024; k += 64) ((int*)bkt)[k] = src[k];
  sbase[tid] = starts[bh * 512 + h * 64 + tid];
  for (int k = tid; k < 64 * 65; k += 64) hist[k] = 0;
  __syncthreads();

  {
    int c = tid;
    for (int k = 0; k < 64; ++k) {
      int t = c * 64 + k;
      int bin = bkt[t];
      int r = hist[c * 65 + bin];
      hist[c * 65 + bin] = r + 1;
      lrk[t] = (uint8_t)r;
    }
  }
  __syncthreads();
  {
    int bb = tid; int run = 0;
    for (int c2 = 0; c2 < 64; ++c2) {
      int val = hist[c2 * 65 + bb];
      hist[c2 * 65 + bb] = run;
      run += val;
    }
  }
  __syncthreads();
  {
    int c = tid;
    int* dst = sorted + (size_t)bh * 32768;
    for (int k = 0; k < 64; ++k) {
      int t = c * 64 + k;
      int bin = bkt[t];
      int pos = sbase[bin] + hist[c * 65 + bin] + (int)lrk[t];
      dst[pos] = h * 4096 + t;
    }
  }
}

// ============================================================
// K3: chunked attention, fp16 MFMA.
// kf: K/Q rows [j=128][f=64] fp16, 16B-slot XOR swizzle ^(row&7).
// vt: V^T [d=64][j=128] fp16, slot ^(d&15).
// P [q=64][j=128] fp16 aliases kf, slot ^(q&15).
// Dots: S^T[j][q] = K * Q^T, 1 fp16 MFMA per k-step.
// Softmax in exp2 domain (log2e folded into inv_norm).
// PV: O = P * V (A=P rows, B=V^T rows); 1/sum folded post-PV.
// ============================================================
__global__ __launch_bounds__(256, 4) void k_attn(const float* __restrict__ qk,
                                                 const float* __restrict__ vin,
                                                 const int* __restrict__ sorted,
                                                 _Float16* __restrict__ o_buf,
                                                 float* __restrict__ lse_buf) {
  __shared__ __attribute__((aligned(16))) _Float16 kf[128 * 64];
  __shared__ __attribute__((aligned(16))) _Float16 vt[64 * 128];
  __shared__ __attribute__((aligned(16))) float norms_inv[128];  // log2e/||k||
  __shared__ __attribute__((aligned(16))) float pinv_s[64];
  __shared__ __attribute__((aligned(16))) int tv[128];
  __shared__ __attribute__((aligned(16))) int items[64];

  int tid = threadIdx.x;
  int bh = blockIdx.x >> 9;
  int c  = blockIdx.x & 511;
  int b = bh >> 3, head = bh & 7;

  // ---- step 1: item ids for 64 current + 64 look-back rows ----
  if (tid < 128) {
    int r = tid;
    int pos = (r < 64) ? (c * 64 + r) : (((c + 511) & 511) * 64 + (r - 64));
    int item = sorted[(size_t)bh * 32768 + pos];
    tv[r] = item & 4095;
    if (r < 64) items[r] = item;
  }
  __syncthreads();

  // ---- step 2a: gather K/Q rows -> kf (fp16), norms ----
  {
    int r = tid >> 1, h = tid & 1;
    int t = tv[r];
    const float4* src = (const float4*)(qk + ((size_t)((b * 4096 + t) * 8 + head)) * 64 + h * 32);
    float x[32];
    float ss = 0.f;
#pragma unroll
    for (int i = 0; i < 8; ++i) {
      float4 v = src[i];
      x[4 * i + 0] = v.x; x[4 * i + 1] = v.y; x[4 * i + 2] = v.z; x[4 * i + 3] = v.w;
      ss = fmaf(v.x, v.x, ss); ss = fmaf(v.y, v.y, ss);
      ss = fmaf(v.z, v.z, ss); ss = fmaf(v.w, v.w, ss);
    }
    ss += __shfl_xor(ss, 1);
    if (h == 0) norms_inv[r] = LOG2E / fmaxf(sqrtf(ss), 1e-12f);
    int rx = r & 7;
#pragma unroll
    for (int s4 = 0; s4 < 4; ++s4) {
      int slot = 4 * h + s4;
      f16x8 hv;
#pragma unroll
      for (int e = 0; e < 8; ++e) hv[e] = (_Float16)x[8 * s4 + e];
      *(f16x8*)&kf[r * 64 + ((slot ^ rx) << 3)] = hv;
    }
  }

  // ---- step 2b: gather V -> vt (transposed, fp16) ----
  {
    int jp = tid & 63, cq = tid >> 6, f0 = cq * 16;
    int t0 = tv[2 * jp], t1 = tv[2 * jp + 1];
    const float4* s0 = (const float4*)(vin + ((size_t)((b * 4096 + t0) * 8 + head)) * 64 + f0);
    const float4* s1 = (const float4*)(vin + ((size_t)((b * 4096 + t1) * 8 + head)) * 64 + f0);
    float y0[16], y1[16];
#pragma unroll
    for (int i = 0; i < 4; ++i) {
      float4 a = s0[i], bb2 = s1[i];
      y0[4 * i + 0] = a.x; y0[4 * i + 1] = a.y; y0[4 * i + 2] = a.z; y0[4 * i + 3] = a.w;
      y1[4 * i + 0] = bb2.x; y1[4 * i + 1] = bb2.y; y1[4 * i + 2] = bb2.z; y1[4 * i + 3] = bb2.w;
    }
#pragma unroll
    for (int i = 0; i < 16; ++i) {
      int d = f0 + i;
      unsigned pack = (unsigned)f2h_bits(y0[i]) | ((unsigned)f2h_bits(y1[i]) << 16);
      *(unsigned*)&vt[d * 128 + (((jp >> 2) ^ (d & 15)) << 3) + ((jp & 3) << 1)] = pack;
    }
  }
  __syncthreads();

  // ---- step 3: dots S^T = K * Q^T (fp16) ----
  int w = tid >> 6;
  int l = tid & 63;
  int col = l & 15;
  int kg = l >> 4;
  int rq = w * 16 + col;
  int rqx7 = rq & 7, rqx15 = rq & 15;

  f16x8 qf[2];
#pragma unroll
  for (int ks = 0; ks < 2; ++ks)
    qf[ks] = *(f16x8*)&kf[rq * 64 + (((ks * 4 + kg) ^ rqx7) << 3)];

  f32x4 S[8];
#pragma unroll
  for (int mt = 0; mt < 8; ++mt) S[mt] = (f32x4){0.f, 0.f, 0.f, 0.f};

  __builtin_amdgcn_s_setprio(1);
#pragma unroll
  for (int mt = 0; mt < 8; ++mt) {
    int rj = mt * 16 + col;
    int rjx = rj & 7;
#pragma unroll
    for (int ks = 0; ks < 2; ++ks) {
      f16x8 a = *(f16x8*)&kf[rj * 64 + (((ks * 4 + kg) ^ rjx) << 3)];
      S[mt] = __builtin_amdgcn_mfma_f32_16x16x32_f16(a, qf[ks], S[mt], 0, 0, 0);
    }
  }
  __builtin_amdgcn_s_setprio(0);

  // ---- step 4: scale (log2 domain), self-mask, softmax over j ----
  int tq = tv[rq];
  float vals[32];
  float mx = -1e30f;
#pragma unroll
  for (int mt = 0; mt < 8; ++mt) {
    int j0 = mt * 16 + kg * 4;
    int4   tk4 = *(int4*)&tv[j0];
    float4 ni4 = *(float4*)&norms_inv[j0];
    int   tki[4] = {tk4.x, tk4.y, tk4.z, tk4.w};
    float nii[4] = {ni4.x, ni4.y, ni4.z, ni4.w};
#pragma unroll
    for (int r = 0; r < 4; ++r) {
      float d = S[mt][r] * nii[r];
      if (tki[r] == tq) d = -50000.0f * LOG2E;
      vals[mt * 4 + r] = d;
      mx = fmaxf(mx, d);
    }
  }
  mx = fmaxf(mx, __shfl_xor(mx, 16));
  mx = fmaxf(mx, __shfl_xor(mx, 32));
  float ssum = 0.f;
#pragma unroll
  for (int i = 0; i < 32; ++i) {
    float e = __builtin_amdgcn_exp2f(vals[i] - mx);
    vals[i] = e;
    ssum += e;
  }
  ssum += __shfl_xor(ssum, 16);
  ssum += __shfl_xor(ssum, 32);
  if (kg == 0) {
    int item = items[rq];
    lse_buf[(size_t)(bh * 8 + (item >> 12)) * 4096 + (item & 4095)] =
        (mx + __builtin_amdgcn_logf(ssum)) * LN2;
    pinv_s[rq] = 1.f / ssum;
  }

  __syncthreads();   // all waves done reading kf as K/Q

  // ---- step 5: write P (fp16, unnormalized) into kf alias ----
  _Float16* Pb = kf;
#pragma unroll
  for (int mt = 0; mt < 8; ++mt) {
    int j0 = mt * 16 + kg * 4;
    int slot = j0 >> 3;
    int off = rq * 128 + ((slot ^ rqx15) << 3) + ((kg & 1) << 2);
    f16x4 pk;
#pragma unroll
    for (int r = 0; r < 4; ++r) pk[r] = (_Float16)vals[mt * 4 + r];
    *(f16x4*)&Pb[off] = pk;
  }
  asm volatile("s_waitcnt lgkmcnt(0)" ::: "memory");

  // ---- step 6: PV = P * V ----
  f32x4 O[4];
#pragma unroll
  for (int nt = 0; nt < 4; ++nt) O[nt] = (f32x4){0.f, 0.f, 0.f, 0.f};
  __builtin_amdgcn_s_setprio(1);
#pragma unroll
  for (int ks = 0; ks < 4; ++ks) {
    int slot = (ks << 2) + kg;
    f16x8 pa = *(f16x8*)&Pb[rq * 128 + ((slot ^ rqx15) << 3)];
#pragma unroll
    for (int nt = 0; nt < 4; ++nt) {
      int dD = nt * 16 + col;
      f16x8 vb = *(f16x8*)&vt[dD * 128 + ((slot ^ (dD & 15)) << 3)];
      O[nt] = __builtin_amdgcn_mfma_f32_16x16x32_f16(pa, vb, O[nt], 0, 0, 0);
    }
  }
  __builtin_amdgcn_s_setprio(0);

  // ---- step 7: scale by 1/sum, scatter O (fp16) ----
  {
    int i0 = w * 16 + kg * 4;
    int4 it4 = *(int4*)&items[i0];
    float4 pv4 = *(float4*)&pinv_s[i0];
    int iti[4] = {it4.x, it4.y, it4.z, it4.w};
    float pvi[4] = {pv4.x, pv4.y, pv4.z, pv4.w};
#pragma unroll
    for (int r = 0; r < 4; ++r) {
      int item = iti[r];
      _Float16* orow = o_buf + ((size_t)((bh * 8 + (item >> 12)) * 4096 + (item & 4095))) * 64;
#pragma unroll
      for (int nt = 0; nt < 4; ++nt) orow[nt * 16 + col] = (_Float16)(O[nt][r] * pvi[r]);
    }
  }
}

// ============================================================
// K4: combine 8 hash rounds (fp16 o_buf)
// ============================================================
__global__ __launch_bounds__(256) void k_combine(const _Float16* __restrict__ o_buf,
                                                 const float* __restrict__ lse_buf,
                                                 float* __restrict__ out) {
  int gid = blockIdx.x * 256 + threadIdx.x;  // < 16*4096*16
  int d4 = gid & 15;
  int t  = (gid >> 4) & 4095;
  int bh = gid >> 16;

  float lx[8];
#pragma unroll
  for (int h = 0; h < 8; ++h) lx[h] = lse_buf[(size_t)(bh * 8 + h) * 4096 + t];
  float m = lx[0];
#pragma unroll
  for (int h = 1; h < 8; ++h) m = fmaxf(m, lx[h]);
  float wv[8]; float s = 0.f;
#pragma unroll
  for (int h = 0; h < 8; ++h) { wv[h] = __expf(lx[h] - m); s += wv[h]; }
  float inv = 1.f / s;

  float ax = 0.f, ay = 0.f, az = 0.f, aw = 0.f;
#pragma unroll
  for (int h = 0; h < 8; ++h) {
    f16x4 ov = *(const f16x4*)(o_buf +
        ((size_t)((bh * 8 + h) * 4096 + t)) * 64 + d4 * 4);
    ax = fmaf(wv[h], (float)ov[0], ax);
    ay = fmaf(wv[h], (float)ov[1], ay);
    az = fmaf(wv[h], (float)ov[2], az);
    aw = fmaf(wv[h], (float)ov[3], aw);
  }
  *(float4*)(out + ((size_t)(bh * 4096 + t)) * 64 + d4 * 4) =
      make_float4(ax * inv, ay * inv, az * inv, aw * inv);
}

// ============================================================
extern "C" void kernel_launch(void* const* d_in, const int* in_sizes, int n_in,
                              void* d_out, int out_size, void* d_ws, size_t ws_size,
                              hipStream_t stream) {
  const float* qk  = (const float*)d_in[0];
  // d_in[1] ("k") is unused by the reference
  const float* vin = (const float*)d_in[2];
  const float* rot = (const float*)d_in[3];

  uint8_t* ws = (uint8_t*)d_ws;
  uint8_t*  buckets = ws + WS_BUCKETS;
  int*      counts  = (int*)(ws + WS_STARTS);
  int*      sorted  = (int*)(ws + WS_SORTED);
  float*    lse_buf = (float*)(ws + WS_LSE);
  _Float16* o_buf   = (_Float16*)(ws + WS_O);
  float*    out     = (float*)d_out;

  hipMemsetAsync(counts, 0, BHN * GBUCK * sizeof(int), stream);
  k_hash<<<1024, 256, 0, stream>>>(qk, rot, buckets, counts);
  k_scan<<<BHN, 512, 0, stream>>>(counts);
  k_rank<<<BHN * NHASH, 64, 0, stream>>>(buckets, counts, sorted);
  k_attn<<<BHN * NCHUNK, 256, 0, stream>>>(qk, vin, sorted, o_buf, lse_buf);
  k_combine<<<4096, 256, 0, stream>>>(o_buf, lse_buf, out);
}

// Round 4
// 190.592 us; speedup vs baseline: 1.1241x; 1.1241x over previous
//
#include <hip/hip_runtime.h>
#include <stdint.h>

// ---------------- problem constants ----------------
#define BHN 16          // b*h flat batch
#define TLEN 4096
#define EDIM 64
#define NHASH 8
#define NBUCK 64
#define GBUCK 512
#define NCHUNK 512
#define NITEMS 32768

// ---------------- workspace layout (bytes) ----------------
#define WS_BUCKETS 0u                 // 16*8*4096 u8          = 524288
#define WS_STARTS  524288u            // 16*512 int            = 32768
#define WS_SORTED  557056u            // 16*32768 int          = 2097152
#define WS_LSE     2654208u           // 16*8*4096 f32         = 2097152
#define WS_O       4751360u           // 16*8*4096*64 fp16     = 67108864

typedef __attribute__((ext_vector_type(4))) float f32x4;
typedef __attribute__((ext_vector_type(8))) _Float16 f16x8;     // MFMA A/B frag
typedef __attribute__((ext_vector_type(4))) _Float16 f16x4;

#define LOG2E 1.44269504088896f
#define LN2   0.69314718055995f

static __device__ __forceinline__ unsigned short f2h_bits(float x) {
  _Float16 h = (_Float16)x;
  return *(unsigned short*)&h;
}

// ============================================================
// K1: LSH hash — zero-LDS, rotations via SGPR (scalar cache).
// block -> (bh, hp, tblk) derived from blockIdx ONLY, so the
// rot address is provably wave-uniform -> s_load_dwordx16.
// Inner loop: 32 pure v_fma_f32 (VGPR qf/acc, SGPR rot).
// fmaf order (f ascending) and argmax scan are IDENTICAL to
// the passing rounds -> bit-identical buckets.
// ============================================================
__global__ __launch_bounds__(256) void k_hash(const float* __restrict__ qk,
                                              const float* __restrict__ rot,
                                              uint8_t* __restrict__ buckets,
                                              int* __restrict__ counts) {
  int tid = threadIdx.x;
  int blk = blockIdx.x;                 // 1024 blocks
  int bh   = blk >> 6;                  // 16
  int hp   = (blk >> 4) & 3;            // 4 hash pairs
  int tblk = blk & 15;                  // 16 token tiles
  int t = tblk * 256 + tid;
  int b = bh >> 3, head = bh & 7;

  const float4* row4 = (const float4*)(qk + ((size_t)((b * 4096 + t) * 8 + head)) * 64);
  float q[64];
#pragma unroll
  for (int f4 = 0; f4 < 16; ++f4) {
    float4 vv = row4[f4];
    q[4 * f4 + 0] = vv.x; q[4 * f4 + 1] = vv.y;
    q[4 * f4 + 2] = vv.z; q[4 * f4 + 3] = vv.w;
  }

  for (int hh = 0; hh < 2; ++hh) {
    int h = hp * 2 + hh;
    const float* rbase = rot + h * 32;  // rot[f][h][i] at f*256 + h*32 + i
    float acc[32];
#pragma unroll
    for (int i = 0; i < 32; ++i) acc[i] = 0.f;

#pragma unroll 4
    for (int f = 0; f < 64; ++f) {
      float qf = q[f];
      const float* rp = rbase + f * 256;   // wave-uniform -> s_load
#pragma unroll
      for (int i = 0; i < 32; ++i)
        acc[i] = fmaf(qf, rp[i], acc[i]);
    }

    // argmax over concat([rot, -rot]), first-max semantics
    float bv = acc[0]; int bi = 0;
#pragma unroll
    for (int i = 1; i < 32; ++i) { if (acc[i] > bv) { bv = acc[i]; bi = i; } }
#pragma unroll
    for (int i = 0; i < 32; ++i) { float nv = -acc[i]; if (nv > bv) { bv = nv; bi = i + 32; } }

    buckets[(bh * 8 + h) * 4096 + t] = (uint8_t)bi;
    atomicAdd(&counts[bh * 512 + h * 64 + bi], 1);
  }
}

// ============================================================
// K2a: exclusive scan (unchanged)
// ============================================================
__global__ __launch_bounds__(512) void k_scan(int* __restrict__ counts) {
  __shared__ int s[512];
  int tid = threadIdx.x;
  int bh = blockIdx.x;
  s[tid] = counts[bh * 512 + tid];
  __syncthreads();
#pragma unroll
  for (int off = 1; off < 512; off <<= 1) {
    int v = (tid >= off) ? s[tid - off] : 0;
    __syncthreads();
    s[tid] += v;
    __syncthreads();
  }
  counts[bh * 512 + tid] = (tid == 0) ? 0 : s[tid - 1];
}

// ============================================================
// K2b: stable rank + scatter (unchanged)
// ============================================================
__global__ __launch_bounds__(64) void k_rank(const uint8_t* __restrict__ buckets,
                                             const int* __restrict__ starts,
                                             int* __restrict__ sorted) {
  __shared__ uint8_t bkt[4096];
  __shared__ uint8_t lrk[4096];
  __shared__ int hist[64 * 65];
  __shared__ int sbase[64];
  int tid = threadIdx.x;
  int bh = blockIdx.x >> 3, h = blockIdx.x & 7;

  const int* src = (const int*)(buckets + (size_t)(bh * 8 + h) * 4096);
  for (int k = tid; k < 1024; k += 64) ((int*)bkt)[k] = src[k];
  sbase[tid] = starts[bh * 512 + h * 64 + tid];
  for (int k = tid; k < 64 * 65; k += 64) hist[k] = 0;
  __syncthreads();

  {
    int c = tid;
    for (int k = 0; k < 64; ++k) {
      int t = c * 64 + k;
      int bin = bkt[t];
      int r = hist[c * 65 + bin];
      hist[c * 65 + bin] = r + 1;
      lrk[t] = (uint8_t)r;
    }
  }
  __syncthreads();
  {
    int bb = tid; int run = 0;
    for (int c2 = 0; c2 < 64; ++c2) {
      int val = hist[c2 * 65 + bb];
      hist[c2 * 65 + bb] = run;
      run += val;
    }
  }
  __syncthreads();
  {
    int c = tid;
    int* dst = sorted + (size_t)bh * 32768;
    for (int k = 0; k < 64; ++k) {
      int t = c * 64 + k;
      int bin = bkt[t];
      int pos = sbase[bin] + hist[c * 65 + bin] + (int)lrk[t];
      dst[pos] = h * 4096 + t;
    }
  }
}

// ============================================================
// K3: chunked attention, fp16 MFMA (unchanged from round 2)
// ============================================================
__global__ __launch_bounds__(256, 4) void k_attn(const float* __restrict__ qk,
                                                 const float* __restrict__ vin,
                                                 const int* __restrict__ sorted,
                                                 _Float16* __restrict__ o_buf,
                                                 float* __restrict__ lse_buf) {
  __shared__ __attribute__((aligned(16))) _Float16 kf[128 * 64];
  __shared__ __attribute__((aligned(16))) _Float16 vt[64 * 128];
  __shared__ __attribute__((aligned(16))) float norms_inv[128];  // log2e/||k||
  __shared__ __attribute__((aligned(16))) float pinv_s[64];
  __shared__ __attribute__((aligned(16))) int tv[128];
  __shared__ __attribute__((aligned(16))) int items[64];

  int tid = threadIdx.x;
  int bh = blockIdx.x >> 9;
  int c  = blockIdx.x & 511;
  int b = bh >> 3, head = bh & 7;

  // ---- step 1: item ids for 64 current + 64 look-back rows ----
  if (tid < 128) {
    int r = tid;
    int pos = (r < 64) ? (c * 64 + r) : (((c + 511) & 511) * 64 + (r - 64));
    int item = sorted[(size_t)bh * 32768 + pos];
    tv[r] = item & 4095;
    if (r < 64) items[r] = item;
  }
  __syncthreads();

  // ---- step 2a: gather K/Q rows -> kf (fp16), norms ----
  {
    int r = tid >> 1, h = tid & 1;
    int t = tv[r];
    const float4* src = (const float4*)(qk + ((size_t)((b * 4096 + t) * 8 + head)) * 64 + h * 32);
    float x[32];
    float ss = 0.f;
#pragma unroll
    for (int i = 0; i < 8; ++i) {
      float4 v = src[i];
      x[4 * i + 0] = v.x; x[4 * i + 1] = v.y; x[4 * i + 2] = v.z; x[4 * i + 3] = v.w;
      ss = fmaf(v.x, v.x, ss); ss = fmaf(v.y, v.y, ss);
      ss = fmaf(v.z, v.z, ss); ss = fmaf(v.w, v.w, ss);
    }
    ss += __shfl_xor(ss, 1);
    if (h == 0) norms_inv[r] = LOG2E / fmaxf(sqrtf(ss), 1e-12f);
    int rx = r & 7;
#pragma unroll
    for (int s4 = 0; s4 < 4; ++s4) {
      int slot = 4 * h + s4;
      f16x8 hv;
#pragma unroll
      for (int e = 0; e < 8; ++e) hv[e] = (_Float16)x[8 * s4 + e];
      *(f16x8*)&kf[r * 64 + ((slot ^ rx) << 3)] = hv;
    }
  }

  // ---- step 2b: gather V -> vt (transposed, fp16) ----
  {
    int jp = tid & 63, cq = tid >> 6, f0 = cq * 16;
    int t0 = tv[2 * jp], t1 = tv[2 * jp + 1];
    const float4* s0 = (const float4*)(vin + ((size_t)((b * 4096 + t0) * 8 + head)) * 64 + f0);
    const float4* s1 = (const float4*)(vin + ((size_t)((b * 4096 + t1) * 8 + head)) * 64 + f0);
    float y0[16], y1[16];
#pragma unroll
    for (int i = 0; i < 4; ++i) {
      float4 a = s0[i], bb2 = s1[i];
      y0[4 * i + 0] = a.x; y0[4 * i + 1] = a.y; y0[4 * i + 2] = a.z; y0[4 * i + 3] = a.w;
      y1[4 * i + 0] = bb2.x; y1[4 * i + 1] = bb2.y; y1[4 * i + 2] = bb2.z; y1[4 * i + 3] = bb2.w;
    }
#pragma unroll
    for (int i = 0; i < 16; ++i) {
      int d = f0 + i;
      unsigned pack = (unsigned)f2h_bits(y0[i]) | ((unsigned)f2h_bits(y1[i]) << 16);
      *(unsigned*)&vt[d * 128 + (((jp >> 2) ^ (d & 15)) << 3) + ((jp & 3) << 1)] = pack;
    }
  }
  __syncthreads();

  // ---- step 3: dots S^T = K * Q^T (fp16) ----
  int w = tid >> 6;
  int l = tid & 63;
  int col = l & 15;
  int kg = l >> 4;
  int rq = w * 16 + col;
  int rqx7 = rq & 7, rqx15 = rq & 15;

  f16x8 qf[2];
#pragma unroll
  for (int ks = 0; ks < 2; ++ks)
    qf[ks] = *(f16x8*)&kf[rq * 64 + (((ks * 4 + kg) ^ rqx7) << 3)];

  f32x4 S[8];
#pragma unroll
  for (int mt = 0; mt < 8; ++mt) S[mt] = (f32x4){0.f, 0.f, 0.f, 0.f};

  __builtin_amdgcn_s_setprio(1);
#pragma unroll
  for (int mt = 0; mt < 8; ++mt) {
    int rj = mt * 16 + col;
    int rjx = rj & 7;
#pragma unroll
    for (int ks = 0; ks < 2; ++ks) {
      f16x8 a = *(f16x8*)&kf[rj * 64 + (((ks * 4 + kg) ^ rjx) << 3)];
      S[mt] = __builtin_amdgcn_mfma_f32_16x16x32_f16(a, qf[ks], S[mt], 0, 0, 0);
    }
  }
  __builtin_amdgcn_s_setprio(0);

  // ---- step 4: scale (log2 domain), self-mask, softmax over j ----
  int tq = tv[rq];
  float vals[32];
  float mx = -1e30f;
#pragma unroll
  for (int mt = 0; mt < 8; ++mt) {
    int j0 = mt * 16 + kg * 4;
    int4   tk4 = *(int4*)&tv[j0];
    float4 ni4 = *(float4*)&norms_inv[j0];
    int   tki[4] = {tk4.x, tk4.y, tk4.z, tk4.w};
    float nii[4] = {ni4.x, ni4.y, ni4.z, ni4.w};
#pragma unroll
    for (int r = 0; r < 4; ++r) {
      float d = S[mt][r] * nii[r];
      if (tki[r] == tq) d = -50000.0f * LOG2E;
      vals[mt * 4 + r] = d;
      mx = fmaxf(mx, d);
    }
  }
  mx = fmaxf(mx, __shfl_xor(mx, 16));
  mx = fmaxf(mx, __shfl_xor(mx, 32));
  float ssum = 0.f;
#pragma unroll
  for (int i = 0; i < 32; ++i) {
    float e = __builtin_amdgcn_exp2f(vals[i] - mx);
    vals[i] = e;
    ssum += e;
  }
  ssum += __shfl_xor(ssum, 16);
  ssum += __shfl_xor(ssum, 32);
  if (kg == 0) {
    int item = items[rq];
    lse_buf[(size_t)(bh * 8 + (item >> 12)) * 4096 + (item & 4095)] =
        (mx + __builtin_amdgcn_logf(ssum)) * LN2;
    pinv_s[rq] = 1.f / ssum;
  }

  __syncthreads();   // all waves done reading kf as K/Q

  // ---- step 5: write P (fp16, unnormalized) into kf alias ----
  _Float16* Pb = kf;
#pragma unroll
  for (int mt = 0; mt < 8; ++mt) {
    int j0 = mt * 16 + kg * 4;
    int slot = j0 >> 3;
    int off = rq * 128 + ((slot ^ rqx15) << 3) + ((kg & 1) << 2);
    f16x4 pk;
#pragma unroll
    for (int r = 0; r < 4; ++r) pk[r] = (_Float16)vals[mt * 4 + r];
    *(f16x4*)&Pb[off] = pk;
  }
  asm volatile("s_waitcnt lgkmcnt(0)" ::: "memory");

  // ---- step 6: PV = P * V ----
  f32x4 O[4];
#pragma unroll
  for (int nt = 0; nt < 4; ++nt) O[nt] = (f32x4){0.f, 0.f, 0.f, 0.f};
  __builtin_amdgcn_s_setprio(1);
#pragma unroll
  for (int ks = 0; ks < 4; ++ks) {
    int slot = (ks << 2) + kg;
    f16x8 pa = *(f16x8*)&Pb[rq * 128 + ((slot ^ rqx15) << 3)];
#pragma unroll
    for (int nt = 0; nt < 4; ++nt) {
      int dD = nt * 16 + col;
      f16x8 vb = *(f16x8*)&vt[dD * 128 + ((slot ^ (dD & 15)) << 3)];
      O[nt] = __builtin_amdgcn_mfma_f32_16x16x32_f16(pa, vb, O[nt], 0, 0, 0);
    }
  }
  __builtin_amdgcn_s_setprio(0);

  // ---- step 7: scale by 1/sum, scatter O (fp16) ----
  {
    int i0 = w * 16 + kg * 4;
    int4 it4 = *(int4*)&items[i0];
    float4 pv4 = *(float4*)&pinv_s[i0];
    int iti[4] = {it4.x, it4.y, it4.z, it4.w};
    float pvi[4] = {pv4.x, pv4.y, pv4.z, pv4.w};
#pragma unroll
    for (int r = 0; r < 4; ++r) {
      int item = iti[r];
      _Float16* orow = o_buf + ((size_t)((bh * 8 + (item >> 12)) * 4096 + (item & 4095))) * 64;
#pragma unroll
      for (int nt = 0; nt < 4; ++nt) orow[nt * 16 + col] = (_Float16)(O[nt][r] * pvi[r]);
    }
  }
}

// ============================================================
// K4: combine 8 hash rounds (unchanged)
// ============================================================
__global__ __launch_bounds__(256) void k_combine(const _Float16* __restrict__ o_buf,
                                                 const float* __restrict__ lse_buf,
                                                 float* __restrict__ out) {
  int gid = blockIdx.x * 256 + threadIdx.x;  // < 16*4096*16
  int d4 = gid & 15;
  int t  = (gid >> 4) & 4095;
  int bh = gid >> 16;

  float lx[8];
#pragma unroll
  for (int h = 0; h < 8; ++h) lx[h] = lse_buf[(size_t)(bh * 8 + h) * 4096 + t];
  float m = lx[0];
#pragma unroll
  for (int h = 1; h < 8; ++h) m = fmaxf(m, lx[h]);
  float wv[8]; float s = 0.f;
#pragma unroll
  for (int h = 0; h < 8; ++h) { wv[h] = __expf(lx[h] - m); s += wv[h]; }
  float inv = 1.f / s;

  float ax = 0.f, ay = 0.f, az = 0.f, aw = 0.f;
#pragma unroll
  for (int h = 0; h < 8; ++h) {
    f16x4 ov = *(const f16x4*)(o_buf +
        ((size_t)((bh * 8 + h) * 4096 + t)) * 64 + d4 * 4);
    ax = fmaf(wv[h], (float)ov[0], ax);
    ay = fmaf(wv[h], (float)ov[1], ay);
    az = fmaf(wv[h], (float)ov[2], az);
    aw = fmaf(wv[h], (float)ov[3], aw);
  }
  *(float4*)(out + ((size_t)(bh * 4096 + t)) * 64 + d4 * 4) =
      make_float4(ax * inv, ay * inv, az * inv, aw * inv);
}

// ============================================================
extern "C" void kernel_launch(void* const* d_in, const int* in_sizes, int n_in,
                              void* d_out, int out_size, void* d_ws, size_t ws_size,
                              hipStream_t stream) {
  const float* qk  = (const float*)d_in[0];
  // d_in[1] ("k") is unused by the reference
  const float* vin = (const float*)d_in[2];
  const float* rot = (const float*)d_in[3];

  uint8_t* ws = (uint8_t*)d_ws;
  uint8_t*  buckets = ws + WS_BUCKETS;
  int*      counts  = (int*)(ws + WS_STARTS);
  int*      sorted  = (int*)(ws + WS_SORTED);
  float*    lse_buf = (float*)(ws + WS_LSE);
  _Float16* o_buf   = (_Float16*)(ws + WS_O);
  float*    out     = (float*)d_out;

  hipMemsetAsync(counts, 0, BHN * GBUCK * sizeof(int), stream);
  k_hash<<<1024, 256, 0, stream>>>(qk, rot, buckets, counts);
  k_scan<<<BHN, 512, 0, stream>>>(counts);
  k_rank<<<BHN * NHASH, 64, 0, stream>>>(buckets, counts, sorted);
  k_attn<<<BHN * NCHUNK, 256, 0, stream>>>(qk, vin, sorted, o_buf, lse_buf);
  k_combine<<<4096, 256, 0, stream>>>(o_buf, lse_buf, out);
}

// Round 5
// 164.908 us; speedup vs baseline: 1.2992x; 1.1557x over previous
//
#include <hip/hip_runtime.h>
#include <stdint.h>

// ---------------- problem constants ----------------
#define BHN 16          // b*h flat batch
#define TLEN 4096
#define EDIM 64
#define NHASH 8
#define NBUCK 64
#define GBUCK 512
#define NCHUNK 512
#define NITEMS 32768

// ---------------- workspace layout (bytes) ----------------
#define WS_BUCKETS 0u                 // 16*8*4096 u8          = 524288
#define WS_STARTS  524288u            // 16*512 int            = 32768
#define WS_SORTED  557056u            // 16*32768 int          = 2097152
#define WS_LSE     2654208u           // 16*8*4096 f32         = 2097152
#define WS_O       4751360u           // 16*8*4096*64 fp16     = 67108864
#define WS_QK16    71860224u          // 16*4096*64 fp16       = 8388608
#define WS_V16     80248832u          // 16*4096*64 fp16       = 8388608
#define WS_NQ      88637440u          // 16*4096 f32           = 262144
// end ~88.9 MB

typedef __attribute__((ext_vector_type(4))) float f32x4;
typedef __attribute__((ext_vector_type(8))) _Float16 f16x8;     // MFMA A/B frag
typedef __attribute__((ext_vector_type(4))) _Float16 f16x4;
typedef __attribute__((ext_vector_type(4))) unsigned u32x4;

#define LOG2E 1.44269504088896f
#define LN2   0.69314718055995f

// ============================================================
// K0: prep — normalize qk rows to fp16, |q|*log2e, v to fp16.
// block = (b, t): 128 threads = (h = tid>>4, e4 = tid&15).
// Coalesced: 512 consecutive floats per tensor per block.
// ============================================================
__global__ __launch_bounds__(128) void k_prep(const float* __restrict__ qk,
                                              const float* __restrict__ vin,
                                              _Float16* __restrict__ qk16n,
                                              _Float16* __restrict__ v16,
                                              float* __restrict__ nq) {
  int blk = blockIdx.x;             // 8192 = b*4096 + t
  int b = blk >> 12, t = blk & 4095;
  int tid = threadIdx.x;
  int h = tid >> 4, e4 = tid & 15;

  size_t in_base = ((size_t)((b * 4096 + t) * 8 + h)) * 64 + e4 * 4;
  float4 qv = *(const float4*)(qk + in_base);
  float ss = qv.x * qv.x + qv.y * qv.y + qv.z * qv.z + qv.w * qv.w;
  ss += __shfl_xor(ss, 1);
  ss += __shfl_xor(ss, 2);
  ss += __shfl_xor(ss, 4);
  ss += __shfl_xor(ss, 8);
  float nrm = fmaxf(sqrtf(ss), 1e-12f);
  float inv = 1.f / nrm;

  size_t out_base = ((size_t)((b * 8 + h) * 4096 + t)) * 64 + e4 * 4;
  f16x4 qh;
  qh[0] = (_Float16)(qv.x * inv); qh[1] = (_Float16)(qv.y * inv);
  qh[2] = (_Float16)(qv.z * inv); qh[3] = (_Float16)(qv.w * inv);
  *(f16x4*)(qk16n + out_base) = qh;
  if (e4 == 0) nq[(size_t)(b * 8 + h) * 4096 + t] = nrm * LOG2E;

  float4 vv = *(const float4*)(vin + in_base);
  f16x4 vh;
  vh[0] = (_Float16)vv.x; vh[1] = (_Float16)vv.y;
  vh[2] = (_Float16)vv.z; vh[3] = (_Float16)vv.w;
  *(f16x4*)(v16 + out_base) = vh;
}

// ============================================================
// K1: LSH hash — zero-LDS, fp32 (must stay fp32: argmax ties).
// Unchanged from round 4.
// ============================================================
__global__ __launch_bounds__(256) void k_hash(const float* __restrict__ qk,
                                              const float* __restrict__ rot,
                                              uint8_t* __restrict__ buckets,
                                              int* __restrict__ counts) {
  int tid = threadIdx.x;
  int blk = blockIdx.x;                 // 1024 blocks
  int bh   = blk >> 6;
  int hp   = (blk >> 4) & 3;
  int tblk = blk & 15;
  int t = tblk * 256 + tid;
  int b = bh >> 3, head = bh & 7;

  const float4* row4 = (const float4*)(qk + ((size_t)((b * 4096 + t) * 8 + head)) * 64);
  float q[64];
#pragma unroll
  for (int f4 = 0; f4 < 16; ++f4) {
    float4 vv = row4[f4];
    q[4 * f4 + 0] = vv.x; q[4 * f4 + 1] = vv.y;
    q[4 * f4 + 2] = vv.z; q[4 * f4 + 3] = vv.w;
  }

  for (int hh = 0; hh < 2; ++hh) {
    int h = hp * 2 + hh;
    const float* rbase = rot + h * 32;
    float acc[32];
#pragma unroll
    for (int i = 0; i < 32; ++i) acc[i] = 0.f;

#pragma unroll 4
    for (int f = 0; f < 64; ++f) {
      float qf = q[f];
      const float* rp = rbase + f * 256;
#pragma unroll
      for (int i = 0; i < 32; ++i)
        acc[i] = fmaf(qf, rp[i], acc[i]);
    }

    float bv = acc[0]; int bi = 0;
#pragma unroll
    for (int i = 1; i < 32; ++i) { if (acc[i] > bv) { bv = acc[i]; bi = i; } }
#pragma unroll
    for (int i = 0; i < 32; ++i) { float nv = -acc[i]; if (nv > bv) { bv = nv; bi = i + 32; } }

    buckets[(bh * 8 + h) * 4096 + t] = (uint8_t)bi;
    atomicAdd(&counts[bh * 512 + h * 64 + bi], 1);
  }
}

// ============================================================
// K2a: exclusive scan (unchanged)
// ============================================================
__global__ __launch_bounds__(512) void k_scan(int* __restrict__ counts) {
  __shared__ int s[512];
  int tid = threadIdx.x;
  int bh = blockIdx.x;
  s[tid] = counts[bh * 512 + tid];
  __syncthreads();
#pragma unroll
  for (int off = 1; off < 512; off <<= 1) {
    int v = (tid >= off) ? s[tid - off] : 0;
    __syncthreads();
    s[tid] += v;
    __syncthreads();
  }
  counts[bh * 512 + tid] = (tid == 0) ? 0 : s[tid - 1];
}

// ============================================================
// K2b: stable rank + scatter (unchanged)
// ============================================================
__global__ __launch_bounds__(64) void k_rank(const uint8_t* __restrict__ buckets,
                                             const int* __restrict__ starts,
                                             int* __restrict__ sorted) {
  __shared__ uint8_t bkt[4096];
  __shared__ uint8_t lrk[4096];
  __shared__ int hist[64 * 65];
  __shared__ int sbase[64];
  int tid = threadIdx.x;
  int bh = blockIdx.x >> 3, h = blockIdx.x & 7;

  const int* src = (const int*)(buckets + (size_t)(bh * 8 + h) * 4096);
  for (int k = tid; k < 1024; k += 64) ((int*)bkt)[k] = src[k];
  sbase[tid] = starts[bh * 512 + h * 64 + tid];
  for (int k = tid; k < 64 * 65; k += 64) hist[k] = 0;
  __syncthreads();

  {
    int c = tid;
    for (int k = 0; k < 64; ++k) {
      int t = c * 64 + k;
      int bin = bkt[t];
      int r = hist[c * 65 + bin];
      hist[c * 65 + bin] = r + 1;
      lrk[t] = (uint8_t)r;
    }
  }
  __syncthreads();
  {
    int bb = tid; int run = 0;
    for (int c2 = 0; c2 < 64; ++c2) {
      int val = hist[c2 * 65 + bb];
      hist[c2 * 65 + bb] = run;
      run += val;
    }
  }
  __syncthreads();
  {
    int c = tid;
    int* dst = sorted + (size_t)bh * 32768;
    for (int k = 0; k < 64; ++k) {
      int t = c * 64 + k;
      int bin = bkt[t];
      int pos = sbase[bin] + hist[c * 65 + bin] + (int)lrk[t];
      dst[pos] = h * 4096 + t;
    }
  }
}

// ============================================================
// K3: chunked attention, fp16 MFMA, pre-converted inputs.
// kf: normalized K/Q rows [128][64] fp16, slot^(row&7) swizzle.
// vt: V^T [64][128] fp16, slot^(d&15).
// P [64][128] fp16 aliases kf, slot^(q&15).
// dots = (K̂·Q̂^T); logits = dots * |q| * log2e (per-lane scale).
// ============================================================
__global__ __launch_bounds__(256, 4) void k_attn(const _Float16* __restrict__ qk16n,
                                                 const _Float16* __restrict__ v16,
                                                 const float* __restrict__ nq,
                                                 const int* __restrict__ sorted,
                                                 _Float16* __restrict__ o_buf,
                                                 float* __restrict__ lse_buf) {
  __shared__ __attribute__((aligned(16))) _Float16 kf[128 * 64];
  __shared__ __attribute__((aligned(16))) _Float16 vt[64 * 128];
  __shared__ __attribute__((aligned(16))) float pinv_s[64];
  __shared__ __attribute__((aligned(16))) int tv[128];
  __shared__ __attribute__((aligned(16))) int items[64];

  int tid = threadIdx.x;
  int bh = blockIdx.x >> 9;
  int c  = blockIdx.x & 511;

  // ---- step 1: item ids for 64 current + 64 look-back rows ----
  if (tid < 128) {
    int r = tid;
    int pos = (r < 64) ? (c * 64 + r) : (((c + 511) & 511) * 64 + (r - 64));
    int item = sorted[(size_t)bh * 32768 + pos];
    tv[r] = item & 4095;
    if (r < 64) items[r] = item;
  }
  __syncthreads();

  int w = tid >> 6;
  int l = tid & 63;
  int col = l & 15;
  int kg = l >> 4;
  int rq = w * 16 + col;
  int rqx7 = rq & 7, rqx15 = rq & 15;
  int tq = tv[rq];
  float nqv = nq[(size_t)bh * 4096 + tq];   // issued early, hides under gather

  // ---- step 2a: gather K/Q rows -> kf (pure fp16 copy) ----
  {
    int r = tid >> 1, half = tid & 1;
    int t = tv[r];
    const f16x8* src = (const f16x8*)(qk16n + ((size_t)(bh * 4096 + t)) * 64 + half * 32);
    f16x8 d0 = src[0], d1 = src[1], d2 = src[2], d3 = src[3];
    int rx = r & 7, s0 = half * 4;
    *(f16x8*)&kf[r * 64 + (((s0 + 0) ^ rx) << 3)] = d0;
    *(f16x8*)&kf[r * 64 + (((s0 + 1) ^ rx) << 3)] = d1;
    *(f16x8*)&kf[r * 64 + (((s0 + 2) ^ rx) << 3)] = d2;
    *(f16x8*)&kf[r * 64 + (((s0 + 3) ^ rx) << 3)] = d3;
  }

  // ---- step 2b: gather V -> vt (transposed via v_perm) ----
  {
    int jp = tid & 63, db = tid >> 6, f0 = db * 16;
    int t0 = tv[2 * jp], t1 = tv[2 * jp + 1];
    const u32x4* s0p = (const u32x4*)(v16 + ((size_t)(bh * 4096 + t0)) * 64 + f0);
    const u32x4* s1p = (const u32x4*)(v16 + ((size_t)(bh * 4096 + t1)) * 64 + f0);
    u32x4 lo0 = s0p[0], hi0 = s0p[1];
    u32x4 lo1 = s1p[0], hi1 = s1p[1];
    int jbase = ((jp >> 2) /*slot*/);
    int joff = (jp & 3) << 1;
#pragma unroll
    for (int i = 0; i < 16; ++i) {
      int d = f0 + i;
      unsigned a = (i < 8) ? lo0[(i >> 1) & 3] : hi0[(i >> 1) & 3];
      unsigned bsrc = (i < 8) ? lo1[(i >> 1) & 3] : hi1[(i >> 1) & 3];
      unsigned sel = (i & 1) ? 0x07060302u : 0x05040100u;
      unsigned pack = __builtin_amdgcn_perm(bsrc, a, sel);
      *(unsigned*)&vt[d * 128 + ((jbase ^ (d & 15)) << 3) + joff] = pack;
    }
  }
  __syncthreads();

  // ---- step 3: dots S^T = K̂ * Q̂^T (fp16) ----
  f16x8 qf[2];
#pragma unroll
  for (int ks = 0; ks < 2; ++ks)
    qf[ks] = *(f16x8*)&kf[rq * 64 + (((ks * 4 + kg) ^ rqx7) << 3)];

  f32x4 S[8];
#pragma unroll
  for (int mt = 0; mt < 8; ++mt) S[mt] = (f32x4){0.f, 0.f, 0.f, 0.f};

  __builtin_amdgcn_s_setprio(1);
#pragma unroll
  for (int mt = 0; mt < 8; ++mt) {
    int rj = mt * 16 + col;
    int rjx = rj & 7;
#pragma unroll
    for (int ks = 0; ks < 2; ++ks) {
      f16x8 a = *(f16x8*)&kf[rj * 64 + (((ks * 4 + kg) ^ rjx) << 3)];
      S[mt] = __builtin_amdgcn_mfma_f32_16x16x32_f16(a, qf[ks], S[mt], 0, 0, 0);
    }
  }
  __builtin_amdgcn_s_setprio(0);

  // ---- step 4: scale by |q|*log2e, self-mask, softmax over j ----
  float vals[32];
  float mx = -1e30f;
#pragma unroll
  for (int mt = 0; mt < 8; ++mt) {
    int j0 = mt * 16 + kg * 4;
    int4 tk4 = *(int4*)&tv[j0];
    int tki[4] = {tk4.x, tk4.y, tk4.z, tk4.w};
#pragma unroll
    for (int r = 0; r < 4; ++r) {
      float d = S[mt][r] * nqv;
      if (tki[r] == tq) d = -50000.0f * LOG2E;
      vals[mt * 4 + r] = d;
      mx = fmaxf(mx, d);
    }
  }
  mx = fmaxf(mx, __shfl_xor(mx, 16));
  mx = fmaxf(mx, __shfl_xor(mx, 32));
  float ssum = 0.f;
#pragma unroll
  for (int i = 0; i < 32; ++i) {
    float e = __builtin_amdgcn_exp2f(vals[i] - mx);
    vals[i] = e;
    ssum += e;
  }
  ssum += __shfl_xor(ssum, 16);
  ssum += __shfl_xor(ssum, 32);
  if (kg == 0) {
    int item = items[rq];
    lse_buf[(size_t)(bh * 8 + (item >> 12)) * 4096 + (item & 4095)] =
        (mx + __builtin_amdgcn_logf(ssum)) * LN2;
    pinv_s[rq] = 1.f / ssum;
  }

  __syncthreads();   // all waves done reading kf as K/Q

  // ---- step 5: write P (fp16, unnormalized) into kf alias ----
  _Float16* Pb = kf;
#pragma unroll
  for (int mt = 0; mt < 8; ++mt) {
    int j0 = mt * 16 + kg * 4;
    int slot = j0 >> 3;
    int off = rq * 128 + ((slot ^ rqx15) << 3) + ((kg & 1) << 2);
    f16x4 pk;
#pragma unroll
    for (int r = 0; r < 4; ++r) pk[r] = (_Float16)vals[mt * 4 + r];
    *(f16x4*)&Pb[off] = pk;
  }
  asm volatile("s_waitcnt lgkmcnt(0)" ::: "memory");

  // ---- step 6: PV = P * V ----
  f32x4 O[4];
#pragma unroll
  for (int nt = 0; nt < 4; ++nt) O[nt] = (f32x4){0.f, 0.f, 0.f, 0.f};
  __builtin_amdgcn_s_setprio(1);
#pragma unroll
  for (int ks = 0; ks < 4; ++ks) {
    int slot = (ks << 2) + kg;
    f16x8 pa = *(f16x8*)&Pb[rq * 128 + ((slot ^ rqx15) << 3)];
#pragma unroll
    for (int nt = 0; nt < 4; ++nt) {
      int dD = nt * 16 + col;
      f16x8 vb = *(f16x8*)&vt[dD * 128 + ((slot ^ (dD & 15)) << 3)];
      O[nt] = __builtin_amdgcn_mfma_f32_16x16x32_f16(pa, vb, O[nt], 0, 0, 0);
    }
  }
  __builtin_amdgcn_s_setprio(0);

  // ---- step 7: scale by 1/sum, scatter O (fp16) ----
  {
    int i0 = w * 16 + kg * 4;
    int4 it4 = *(int4*)&items[i0];
    float4 pv4 = *(float4*)&pinv_s[i0];
    int iti[4] = {it4.x, it4.y, it4.z, it4.w};
    float pvi[4] = {pv4.x, pv4.y, pv4.z, pv4.w};
#pragma unroll
    for (int r = 0; r < 4; ++r) {
      int item = iti[r];
      _Float16* orow = o_buf + ((size_t)((bh * 8 + (item >> 12)) * 4096 + (item & 4095))) * 64;
#pragma unroll
      for (int nt = 0; nt < 4; ++nt) orow[nt * 16 + col] = (_Float16)(O[nt][r] * pvi[r]);
    }
  }
}

// ============================================================
// K4: combine 8 hash rounds (unchanged)
// ============================================================
__global__ __launch_bounds__(256) void k_combine(const _Float16* __restrict__ o_buf,
                                                 const float* __restrict__ lse_buf,
                                                 float* __restrict__ out) {
  int gid = blockIdx.x * 256 + threadIdx.x;  // < 16*4096*16
  int d4 = gid & 15;
  int t  = (gid >> 4) & 4095;
  int bh = gid >> 16;

  float lx[8];
#pragma unroll
  for (int h = 0; h < 8; ++h) lx[h] = lse_buf[(size_t)(bh * 8 + h) * 4096 + t];
  float m = lx[0];
#pragma unroll
  for (int h = 1; h < 8; ++h) m = fmaxf(m, lx[h]);
  float wv[8]; float s = 0.f;
#pragma unroll
  for (int h = 0; h < 8; ++h) { wv[h] = __expf(lx[h] - m); s += wv[h]; }
  float inv = 1.f / s;

  float ax = 0.f, ay = 0.f, az = 0.f, aw = 0.f;
#pragma unroll
  for (int h = 0; h < 8; ++h) {
    f16x4 ov = *(const f16x4*)(o_buf +
        ((size_t)((bh * 8 + h) * 4096 + t)) * 64 + d4 * 4);
    ax = fmaf(wv[h], (float)ov[0], ax);
    ay = fmaf(wv[h], (float)ov[1], ay);
    az = fmaf(wv[h], (float)ov[2], az);
    aw = fmaf(wv[h], (float)ov[3], aw);
  }
  *(float4*)(out + ((size_t)(bh * 4096 + t)) * 64 + d4 * 4) =
      make_float4(ax * inv, ay * inv, az * inv, aw * inv);
}

// ============================================================
extern "C" void kernel_launch(void* const* d_in, const int* in_sizes, int n_in,
                              void* d_out, int out_size, void* d_ws, size_t ws_size,
                              hipStream_t stream) {
  const float* qk  = (const float*)d_in[0];
  // d_in[1] ("k") is unused by the reference
  const float* vin = (const float*)d_in[2];
  const float* rot = (const float*)d_in[3];

  uint8_t* ws = (uint8_t*)d_ws;
  uint8_t*  buckets = ws + WS_BUCKETS;
  int*      counts  = (int*)(ws + WS_STARTS);
  int*      sorted  = (int*)(ws + WS_SORTED);
  float*    lse_buf = (float*)(ws + WS_LSE);
  _Float16* o_buf   = (_Float16*)(ws + WS_O);
  _Float16* qk16n   = (_Float16*)(ws + WS_QK16);
  _Float16* v16     = (_Float16*)(ws + WS_V16);
  float*    nqbuf   = (float*)(ws + WS_NQ);
  float*    out     = (float*)d_out;

  hipMemsetAsync(counts, 0, BHN * GBUCK * sizeof(int), stream);
  k_prep<<<8192, 128, 0, stream>>>(qk, vin, qk16n, v16, nqbuf);
  k_hash<<<1024, 256, 0, stream>>>(qk, rot, buckets, counts);
  k_scan<<<BHN, 512, 0, stream>>>(counts);
  k_rank<<<BHN * NHASH, 64, 0, stream>>>(buckets, counts, sorted);
  k_attn<<<BHN * NCHUNK, 256, 0, stream>>>(qk16n, v16, nqbuf, sorted, o_buf, lse_buf);
  k_combine<<<4096, 256, 0, stream>>>(o_buf, lse_buf, out);
}

// Round 6
// 152.592 us; speedup vs baseline: 1.4041x; 1.0807x over previous
//
#include <hip/hip_runtime.h>
#include <stdint.h>

// ---------------- problem constants ----------------
#define BHN 16          // b*h flat batch
#define TLEN 4096
#define EDIM 64
#define NHASH 8
#define NBUCK 64
#define GBUCK 512
#define NCHUNK 512
#define NITEMS 32768

// ---------------- workspace layout (bytes) ----------------
#define WS_BUCKETS 0u                 // 16*8*4096 u8          = 524288
#define WS_STARTS  524288u            // 16*512 int            = 32768
#define WS_SORTED  557056u            // 16*32768 int          = 2097152
#define WS_LSE     2654208u           // 16*8*4096 f32         = 2097152
#define WS_O       4751360u           // 16*8*4096*64 fp16     = 67108864
#define WS_QK16    71860224u          // 16*4096*64 fp16       = 8388608
#define WS_V16     80248832u          // 16*4096*64 fp16       = 8388608
#define WS_NQ      88637440u          // 16*4096 f32           = 262144
// end ~88.9 MB

typedef __attribute__((ext_vector_type(4))) float f32x4;
typedef __attribute__((ext_vector_type(8))) _Float16 f16x8;     // MFMA A/B frag
typedef __attribute__((ext_vector_type(4))) _Float16 f16x4;
typedef __attribute__((ext_vector_type(4))) unsigned u32x4;

#define LOG2E 1.44269504088896f
#define LN2   0.69314718055995f

// ============================================================
// K0: prep — normalize qk rows to fp16, |q|*log2e, v to fp16.
// ============================================================
__global__ __launch_bounds__(128) void k_prep(const float* __restrict__ qk,
                                              const float* __restrict__ vin,
                                              _Float16* __restrict__ qk16n,
                                              _Float16* __restrict__ v16,
                                              float* __restrict__ nq) {
  int blk = blockIdx.x;             // 8192 = b*4096 + t
  int b = blk >> 12, t = blk & 4095;
  int tid = threadIdx.x;
  int h = tid >> 4, e4 = tid & 15;

  size_t in_base = ((size_t)((b * 4096 + t) * 8 + h)) * 64 + e4 * 4;
  float4 qv = *(const float4*)(qk + in_base);
  float ss = qv.x * qv.x + qv.y * qv.y + qv.z * qv.z + qv.w * qv.w;
  ss += __shfl_xor(ss, 1);
  ss += __shfl_xor(ss, 2);
  ss += __shfl_xor(ss, 4);
  ss += __shfl_xor(ss, 8);
  float nrm = fmaxf(sqrtf(ss), 1e-12f);
  float inv = 1.f / nrm;

  size_t out_base = ((size_t)((b * 8 + h) * 4096 + t)) * 64 + e4 * 4;
  f16x4 qh;
  qh[0] = (_Float16)(qv.x * inv); qh[1] = (_Float16)(qv.y * inv);
  qh[2] = (_Float16)(qv.z * inv); qh[3] = (_Float16)(qv.w * inv);
  *(f16x4*)(qk16n + out_base) = qh;
  if (e4 == 0) nq[(size_t)(b * 8 + h) * 4096 + t] = nrm * LOG2E;

  float4 vv = *(const float4*)(vin + in_base);
  f16x4 vh;
  vh[0] = (_Float16)vv.x; vh[1] = (_Float16)vv.y;
  vh[2] = (_Float16)vv.z; vh[3] = (_Float16)vv.w;
  *(f16x4*)(v16 + out_base) = vh;
}

// ============================================================
// K1: LSH hash — zero-LDS, fp32.
// FULL unroll on the f loop: q[f] must be compile-time indexed
// or the compiler demotes q[64] to scratch (rule #20 — round 5
// showed VGPR=32 + 75 MB of scratch traffic with unroll-4).
// fmaf order and argmax scan identical -> bit-identical buckets.
// ============================================================
__global__ __launch_bounds__(256) void k_hash(const float* __restrict__ qk,
                                              const float* __restrict__ rot,
                                              uint8_t* __restrict__ buckets,
                                              int* __restrict__ counts) {
  int tid = threadIdx.x;
  int blk = blockIdx.x;                 // 1024 blocks
  int bh   = blk >> 6;
  int hp   = (blk >> 4) & 3;
  int tblk = blk & 15;
  int t = tblk * 256 + tid;
  int b = bh >> 3, head = bh & 7;

  const float4* row4 = (const float4*)(qk + ((size_t)((b * 4096 + t) * 8 + head)) * 64);
  float q[64];
#pragma unroll
  for (int f4 = 0; f4 < 16; ++f4) {
    float4 vv = row4[f4];
    q[4 * f4 + 0] = vv.x; q[4 * f4 + 1] = vv.y;
    q[4 * f4 + 2] = vv.z; q[4 * f4 + 3] = vv.w;
  }

  for (int hh = 0; hh < 2; ++hh) {
    int h = hp * 2 + hh;
    const float* rbase = rot + h * 32;
    float acc[32];
#pragma unroll
    for (int i = 0; i < 32; ++i) acc[i] = 0.f;

#pragma unroll
    for (int f = 0; f < 64; ++f) {
      float qf = q[f];
      const float* rp = rbase + f * 256;   // wave-uniform -> s_load
#pragma unroll
      for (int i = 0; i < 32; ++i)
        acc[i] = fmaf(qf, rp[i], acc[i]);
    }

    float bv = acc[0]; int bi = 0;
#pragma unroll
    for (int i = 1; i < 32; ++i) { if (acc[i] > bv) { bv = acc[i]; bi = i; } }
#pragma unroll
    for (int i = 0; i < 32; ++i) { float nv = -acc[i]; if (nv > bv) { bv = nv; bi = i + 32; } }

    buckets[(bh * 8 + h) * 4096 + t] = (uint8_t)bi;
    atomicAdd(&counts[bh * 512 + h * 64 + bi], 1);
  }
}

// ============================================================
// K2a: exclusive scan (unchanged)
// ============================================================
__global__ __launch_bounds__(512) void k_scan(int* __restrict__ counts) {
  __shared__ int s[512];
  int tid = threadIdx.x;
  int bh = blockIdx.x;
  s[tid] = counts[bh * 512 + tid];
  __syncthreads();
#pragma unroll
  for (int off = 1; off < 512; off <<= 1) {
    int v = (tid >= off) ? s[tid - off] : 0;
    __syncthreads();
    s[tid] += v;
    __syncthreads();
  }
  counts[bh * 512 + tid] = (tid == 0) ? 0 : s[tid - 1];
}

// ============================================================
// K2b: stable rank + scatter (unchanged)
// ============================================================
__global__ __launch_bounds__(64) void k_rank(const uint8_t* __restrict__ buckets,
                                             const int* __restrict__ starts,
                                             int* __restrict__ sorted) {
  __shared__ uint8_t bkt[4096];
  __shared__ uint8_t lrk[4096];
  __shared__ int hist[64 * 65];
  __shared__ int sbase[64];
  int tid = threadIdx.x;
  int bh = blockIdx.x >> 3, h = blockIdx.x & 7;

  const int* src = (const int*)(buckets + (size_t)(bh * 8 + h) * 4096);
  for (int k = tid; k < 1024; k += 64) ((int*)bkt)[k] = src[k];
  sbase[tid] = starts[bh * 512 + h * 64 + tid];
  for (int k = tid; k < 64 * 65; k += 64) hist[k] = 0;
  __syncthreads();

  {
    int c = tid;
    for (int k = 0; k < 64; ++k) {
      int t = c * 64 + k;
      int bin = bkt[t];
      int r = hist[c * 65 + bin];
      hist[c * 65 + bin] = r + 1;
      lrk[t] = (uint8_t)r;
    }
  }
  __syncthreads();
  {
    int bb = tid; int run = 0;
    for (int c2 = 0; c2 < 64; ++c2) {
      int val = hist[c2 * 65 + bb];
      hist[c2 * 65 + bb] = run;
      run += val;
    }
  }
  __syncthreads();
  {
    int c = tid;
    int* dst = sorted + (size_t)bh * 32768;
    for (int k = 0; k < 64; ++k) {
      int t = c * 64 + k;
      int bin = bkt[t];
      int pos = sbase[bin] + hist[c * 65 + bin] + (int)lrk[t];
      dst[pos] = h * 4096 + t;
    }
  }
}

// ============================================================
// K3: chunked attention, fp16 MFMA (unchanged from round 5)
// ============================================================
__global__ __launch_bounds__(256, 4) void k_attn(const _Float16* __restrict__ qk16n,
                                                 const _Float16* __restrict__ v16,
                                                 const float* __restrict__ nq,
                                                 const int* __restrict__ sorted,
                                                 _Float16* __restrict__ o_buf,
                                                 float* __restrict__ lse_buf) {
  __shared__ __attribute__((aligned(16))) _Float16 kf[128 * 64];
  __shared__ __attribute__((aligned(16))) _Float16 vt[64 * 128];
  __shared__ __attribute__((aligned(16))) float pinv_s[64];
  __shared__ __attribute__((aligned(16))) int tv[128];
  __shared__ __attribute__((aligned(16))) int items[64];

  int tid = threadIdx.x;
  int bh = blockIdx.x >> 9;
  int c  = blockIdx.x & 511;

  // ---- step 1: item ids for 64 current + 64 look-back rows ----
  if (tid < 128) {
    int r = tid;
    int pos = (r < 64) ? (c * 64 + r) : (((c + 511) & 511) * 64 + (r - 64));
    int item = sorted[(size_t)bh * 32768 + pos];
    tv[r] = item & 4095;
    if (r < 64) items[r] = item;
  }
  __syncthreads();

  int w = tid >> 6;
  int l = tid & 63;
  int col = l & 15;
  int kg = l >> 4;
  int rq = w * 16 + col;
  int rqx7 = rq & 7, rqx15 = rq & 15;
  int tq = tv[rq];
  float nqv = nq[(size_t)bh * 4096 + tq];   // issued early, hides under gather

  // ---- step 2a: gather K/Q rows -> kf (pure fp16 copy) ----
  {
    int r = tid >> 1, half = tid & 1;
    int t = tv[r];
    const f16x8* src = (const f16x8*)(qk16n + ((size_t)(bh * 4096 + t)) * 64 + half * 32);
    f16x8 d0 = src[0], d1 = src[1], d2 = src[2], d3 = src[3];
    int rx = r & 7, s0 = half * 4;
    *(f16x8*)&kf[r * 64 + (((s0 + 0) ^ rx) << 3)] = d0;
    *(f16x8*)&kf[r * 64 + (((s0 + 1) ^ rx) << 3)] = d1;
    *(f16x8*)&kf[r * 64 + (((s0 + 2) ^ rx) << 3)] = d2;
    *(f16x8*)&kf[r * 64 + (((s0 + 3) ^ rx) << 3)] = d3;
  }

  // ---- step 2b: gather V -> vt (transposed via v_perm) ----
  {
    int jp = tid & 63, db = tid >> 6, f0 = db * 16;
    int t0 = tv[2 * jp], t1 = tv[2 * jp + 1];
    const u32x4* s0p = (const u32x4*)(v16 + ((size_t)(bh * 4096 + t0)) * 64 + f0);
    const u32x4* s1p = (const u32x4*)(v16 + ((size_t)(bh * 4096 + t1)) * 64 + f0);
    u32x4 lo0 = s0p[0], hi0 = s0p[1];
    u32x4 lo1 = s1p[0], hi1 = s1p[1];
    int jbase = ((jp >> 2) /*slot*/);
    int joff = (jp & 3) << 1;
#pragma unroll
    for (int i = 0; i < 16; ++i) {
      int d = f0 + i;
      unsigned a = (i < 8) ? lo0[(i >> 1) & 3] : hi0[(i >> 1) & 3];
      unsigned bsrc = (i < 8) ? lo1[(i >> 1) & 3] : hi1[(i >> 1) & 3];
      unsigned sel = (i & 1) ? 0x07060302u : 0x05040100u;
      unsigned pack = __builtin_amdgcn_perm(bsrc, a, sel);
      *(unsigned*)&vt[d * 128 + ((jbase ^ (d & 15)) << 3) + joff] = pack;
    }
  }
  __syncthreads();

  // ---- step 3: dots S^T = K̂ * Q̂^T (fp16) ----
  f16x8 qf[2];
#pragma unroll
  for (int ks = 0; ks < 2; ++ks)
    qf[ks] = *(f16x8*)&kf[rq * 64 + (((ks * 4 + kg) ^ rqx7) << 3)];

  f32x4 S[8];
#pragma unroll
  for (int mt = 0; mt < 8; ++mt) S[mt] = (f32x4){0.f, 0.f, 0.f, 0.f};

  __builtin_amdgcn_s_setprio(1);
#pragma unroll
  for (int mt = 0; mt < 8; ++mt) {
    int rj = mt * 16 + col;
    int rjx = rj & 7;
#pragma unroll
    for (int ks = 0; ks < 2; ++ks) {
      f16x8 a = *(f16x8*)&kf[rj * 64 + (((ks * 4 + kg) ^ rjx) << 3)];
      S[mt] = __builtin_amdgcn_mfma_f32_16x16x32_f16(a, qf[ks], S[mt], 0, 0, 0);
    }
  }
  __builtin_amdgcn_s_setprio(0);

  // ---- step 4: scale by |q|*log2e, self-mask, softmax over j ----
  float vals[32];
  float mx = -1e30f;
#pragma unroll
  for (int mt = 0; mt < 8; ++mt) {
    int j0 = mt * 16 + kg * 4;
    int4 tk4 = *(int4*)&tv[j0];
    int tki[4] = {tk4.x, tk4.y, tk4.z, tk4.w};
#pragma unroll
    for (int r = 0; r < 4; ++r) {
      float d = S[mt][r] * nqv;
      if (tki[r] == tq) d = -50000.0f * LOG2E;
      vals[mt * 4 + r] = d;
      mx = fmaxf(mx, d);
    }
  }
  mx = fmaxf(mx, __shfl_xor(mx, 16));
  mx = fmaxf(mx, __shfl_xor(mx, 32));
  float ssum = 0.f;
#pragma unroll
  for (int i = 0; i < 32; ++i) {
    float e = __builtin_amdgcn_exp2f(vals[i] - mx);
    vals[i] = e;
    ssum += e;
  }
  ssum += __shfl_xor(ssum, 16);
  ssum += __shfl_xor(ssum, 32);
  if (kg == 0) {
    int item = items[rq];
    lse_buf[(size_t)(bh * 8 + (item >> 12)) * 4096 + (item & 4095)] =
        (mx + __builtin_amdgcn_logf(ssum)) * LN2;
    pinv_s[rq] = 1.f / ssum;
  }

  __syncthreads();   // all waves done reading kf as K/Q

  // ---- step 5: write P (fp16, unnormalized) into kf alias ----
  _Float16* Pb = kf;
#pragma unroll
  for (int mt = 0; mt < 8; ++mt) {
    int j0 = mt * 16 + kg * 4;
    int slot = j0 >> 3;
    int off = rq * 128 + ((slot ^ rqx15) << 3) + ((kg & 1) << 2);
    f16x4 pk;
#pragma unroll
    for (int r = 0; r < 4; ++r) pk[r] = (_Float16)vals[mt * 4 + r];
    *(f16x4*)&Pb[off] = pk;
  }
  asm volatile("s_waitcnt lgkmcnt(0)" ::: "memory");

  // ---- step 6: PV = P * V ----
  f32x4 O[4];
#pragma unroll
  for (int nt = 0; nt < 4; ++nt) O[nt] = (f32x4){0.f, 0.f, 0.f, 0.f};
  __builtin_amdgcn_s_setprio(1);
#pragma unroll
  for (int ks = 0; ks < 4; ++ks) {
    int slot = (ks << 2) + kg;
    f16x8 pa = *(f16x8*)&Pb[rq * 128 + ((slot ^ rqx15) << 3)];
#pragma unroll
    for (int nt = 0; nt < 4; ++nt) {
      int dD = nt * 16 + col;
      f16x8 vb = *(f16x8*)&vt[dD * 128 + ((slot ^ (dD & 15)) << 3)];
      O[nt] = __builtin_amdgcn_mfma_f32_16x16x32_f16(pa, vb, O[nt], 0, 0, 0);
    }
  }
  __builtin_amdgcn_s_setprio(0);

  // ---- step 7: scale by 1/sum, scatter O (fp16) ----
  {
    int i0 = w * 16 + kg * 4;
    int4 it4 = *(int4*)&items[i0];
    float4 pv4 = *(float4*)&pinv_s[i0];
    int iti[4] = {it4.x, it4.y, it4.z, it4.w};
    float pvi[4] = {pv4.x, pv4.y, pv4.z, pv4.w};
#pragma unroll
    for (int r = 0; r < 4; ++r) {
      int item = iti[r];
      _Float16* orow = o_buf + ((size_t)((bh * 8 + (item >> 12)) * 4096 + (item & 4095))) * 64;
#pragma unroll
      for (int nt = 0; nt < 4; ++nt) orow[nt * 16 + col] = (_Float16)(O[nt][r] * pvi[r]);
    }
  }
}

// ============================================================
// K4: combine 8 hash rounds (unchanged)
// ============================================================
__global__ __launch_bounds__(256) void k_combine(const _Float16* __restrict__ o_buf,
                                                 const float* __restrict__ lse_buf,
                                                 float* __restrict__ out) {
  int gid = blockIdx.x * 256 + threadIdx.x;  // < 16*4096*16
  int d4 = gid & 15;
  int t  = (gid >> 4) & 4095;
  int bh = gid >> 16;

  float lx[8];
#pragma unroll
  for (int h = 0; h < 8; ++h) lx[h] = lse_buf[(size_t)(bh * 8 + h) * 4096 + t];
  float m = lx[0];
#pragma unroll
  for (int h = 1; h < 8; ++h) m = fmaxf(m, lx[h]);
  float wv[8]; float s = 0.f;
#pragma unroll
  for (int h = 0; h < 8; ++h) { wv[h] = __expf(lx[h] - m); s += wv[h]; }
  float inv = 1.f / s;

  float ax = 0.f, ay = 0.f, az = 0.f, aw = 0.f;
#pragma unroll
  for (int h = 0; h < 8; ++h) {
    f16x4 ov = *(const f16x4*)(o_buf +
        ((size_t)((bh * 8 + h) * 4096 + t)) * 64 + d4 * 4);
    ax = fmaf(wv[h], (float)ov[0], ax);
    ay = fmaf(wv[h], (float)ov[1], ay);
    az = fmaf(wv[h], (float)ov[2], az);
    aw = fmaf(wv[h], (float)ov[3], aw);
  }
  *(float4*)(out + ((size_t)(bh * 4096 + t)) * 64 + d4 * 4) =
      make_float4(ax * inv, ay * inv, az * inv, aw * inv);
}

// ============================================================
extern "C" void kernel_launch(void* const* d_in, const int* in_sizes, int n_in,
                              void* d_out, int out_size, void* d_ws, size_t ws_size,
                              hipStream_t stream) {
  const float* qk  = (const float*)d_in[0];
  // d_in[1] ("k") is unused by the reference
  const float* vin = (const float*)d_in[2];
  const float* rot = (const float*)d_in[3];

  uint8_t* ws = (uint8_t*)d_ws;
  uint8_t*  buckets = ws + WS_BUCKETS;
  int*      counts  = (int*)(ws + WS_STARTS);
  int*      sorted  = (int*)(ws + WS_SORTED);
  float*    lse_buf = (float*)(ws + WS_LSE);
  _Float16* o_buf   = (_Float16*)(ws + WS_O);
  _Float16* qk16n   = (_Float16*)(ws + WS_QK16);
  _Float16* v16     = (_Float16*)(ws + WS_V16);
  float*    nqbuf   = (float*)(ws + WS_NQ);
  float*    out     = (float*)d_out;

  hipMemsetAsync(counts, 0, BHN * GBUCK * sizeof(int), stream);
  k_prep<<<8192, 128, 0, stream>>>(qk, vin, qk16n, v16, nqbuf);
  k_hash<<<1024, 256, 0, stream>>>(qk, rot, buckets, counts);
  k_scan<<<BHN, 512, 0, stream>>>(counts);
  k_rank<<<BHN * NHASH, 64, 0, stream>>>(buckets, counts, sorted);
  k_attn<<<BHN * NCHUNK, 256, 0, stream>>>(qk16n, v16, nqbuf, sorted, o_buf, lse_buf);
  k_combine<<<4096, 256, 0, stream>>>(o_buf, lse_buf, out);
}